// Round 1
// baseline (364.430 us; speedup 1.0000x reference)
//
#include <hip/hip_runtime.h>
#include <hip/hip_bf16.h>
#include <math.h>

// Problem constants (from setup_inputs): B=64, H=384, PLTS=16, D=2, grid 25x25.
#define BB    64
#define HH    384
#define PLTS  16
#define LMAX  (HH + PLTS)      // 400
#define NG    25
#define NC    (NG * NG)        // 625
#define BLOCK 640              // 10 waves; one block per batch
#define NWAVES (BLOCK / 64)

#if defined(__has_builtin) && __has_builtin(__builtin_amdgcn_exp2f)
static __device__ __forceinline__ float fast_exp2(float x) { return __builtin_amdgcn_exp2f(x); }
#else
static __device__ __forceinline__ float fast_exp2(float x) { return exp2f(x); }
#endif
#if defined(__has_builtin) && __has_builtin(__builtin_amdgcn_logf)
static __device__ __forceinline__ float fast_log2(float x) { return __builtin_amdgcn_logf(x); }
#else
static __device__ __forceinline__ float fast_log2(float x) { return log2f(x); }
#endif

__global__ __launch_bounds__(BLOCK)
void spatio_kernel(const float* __restrict__ ct,    // curr_time   (B,16)
                   const float* __restrict__ it,    // input_time  (B,384)
                   const float* __restrict__ hd,    // history_data(B,384,2)
                   const float* __restrict__ beta_p,
                   const float* __restrict__ lsig_p,
                   float* __restrict__ out)         // [B loglik | (16,B,2) preds]
{
    __shared__ float  w2s[LMAX];   // beta*log2e * t_j
    __shared__ float  Ejs[LMAX];   // 2^{w2s[j]} = e^{beta t_j}   (gmm phase)
    __shared__ float2 hxy[LMAX];   // history locations
    __shared__ float4 pu[LMAX];    // (u_j, px_j, py_j, 0) for candidate scan
    __shared__ float  rv[NWAVES];
    __shared__ int    ri[NWAVES];
    __shared__ float  sb[4];       // minx,maxx,miny,maxy

    const int b    = blockIdx.x;
    const int tid  = threadIdx.x;
    const int lane = tid & 63;
    const int wave = tid >> 6;

    const float LOG2E  = 1.4426950408889634f;
    const float LN2    = 0.69314718055994531f;
    const float LOG2PI = 1.8378770664093453f;   // log(2*pi)

    const float beta  = beta_p[0];
    const float lsig  = lsig_p[0];
    const float sigma = fast_exp2(lsig * LOG2E);
    const float cc    = -0.5f / (sigma * sigma); // base-e coeff on sq
    const float c2    = cc * LOG2E;              // base-2 coeff on sq
    const float bl    = beta * LOG2E;            // base-2 coeff on t
    const float Sc    = -2.0f * lsig - LOG2PI;   // max logN (d=2)

    // ---- initial history into LDS ----
    for (int j = tid; j < HH; j += BLOCK) {
        float t = it[b * HH + j];
        float x = hd[(b * HH + j) * 2 + 0];
        float y = hd[(b * HH + j) * 2 + 1];
        float w = bl * t;
        w2s[j] = w;
        hxy[j] = make_float2(x, y);
        pu[j]  = make_float4(fmaf(c2, x * x + y * y, w), -2.0f * c2 * x, -2.0f * c2 * y, 0.0f);
    }

    // ---- grid bounds: min/max over history_data[:,0,:] (x) and [:,1,:] (y),
    //      across ALL batches (ref's nd[:,0]/nd[:,1] index axis 1!) ----
    if (tid < 64) {
        const float* p = hd + tid * (HH * 2);
        float p0x = p[0], p0y = p[1], p1x = p[2], p1y = p[3];
        float xmn = fminf(p0x, p0y), xmx = fmaxf(p0x, p0y);
        float ymn = fminf(p1x, p1y), ymx = fmaxf(p1x, p1y);
        for (int o = 32; o > 0; o >>= 1) {
            xmn = fminf(xmn, __shfl_down(xmn, o, 64));
            xmx = fmaxf(xmx, __shfl_down(xmx, o, 64));
            ymn = fminf(ymn, __shfl_down(ymn, o, 64));
            ymx = fmaxf(ymx, __shfl_down(ymx, o, 64));
        }
        if (tid == 0) { sb[0] = xmn; sb[1] = xmx; sb[2] = ymn; sb[3] = ymx; }
    }
    __syncthreads();

    const float minx = sb[0], maxx = sb[1], miny = sb[2], maxy = sb[3];
    const float stepx = (maxx - minx) * (1.0f / 24.0f);
    const float stepy = (maxy - miny) * (1.0f / 24.0f);

    // my candidate (thread tid handles grid point tid): cand[k]=(xlim[k%25], ylim[k/25])
    float cx = 0.0f, cy = 0.0f, Ac = 0.0f;
    if (tid < NC) {
        int kx = tid % NG, ky = tid / NG;
        cx = fmaf((float)kx, stepx, minx);
        cy = fmaf((float)ky, stepy, miny);
        Ac = c2 * (cx * cx + cy * cy);
    }

    // ---- 16 sequential greedy prediction steps ----
    for (int i = 0; i < PLTS; ++i) {
        const int L = HH + i;
        float s;
        int   idx;
        if (tid < NC) {
            // argmin_c ll_c  ==  argmin_c  sum_j exp(beta*t_j - sq_cj/(2 sigma^2))
            // (all candidate-independent terms of ll dropped: monotone map)
            float s0 = 0.0f, s1 = 0.0f;
            int j = 0;
            for (; j + 1 < L; j += 2) {
                float4 pa = pu[j];
                float4 pb = pu[j + 1];
                s0 += fast_exp2(fmaf(pa.y, cx, fmaf(pa.z, cy, pa.x + Ac)));
                s1 += fast_exp2(fmaf(pb.y, cx, fmaf(pb.z, cy, pb.x + Ac)));
            }
            if (j < L) {
                float4 pa = pu[j];
                s0 += fast_exp2(fmaf(pa.y, cx, fmaf(pa.z, cy, pa.x + Ac)));
            }
            s   = s0 + s1;
            idx = tid;
        } else {
            s   = __builtin_inff();
            idx = 0x7fffffff;
        }
        // wave argmin (first-occurrence tie-break, matching jnp.argmin)
        for (int o = 32; o > 0; o >>= 1) {
            float ov = __shfl_down(s, o, 64);
            int   oi = __shfl_down(idx, o, 64);
            if (ov < s || (ov == s && oi < idx)) { s = ov; idx = oi; }
        }
        if (lane == 0) { rv[wave] = s; ri[wave] = idx; }
        __syncthreads();
        if (tid == 0) {
            float bv = rv[0]; int bi = ri[0];
            for (int w = 1; w < NWAVES; ++w) {
                if (rv[w] < bv || (rv[w] == bv && ri[w] < bi)) { bv = rv[w]; bi = ri[w]; }
            }
            float px = fmaf((float)(bi % NG), stepx, minx);
            float py = fmaf((float)(bi / NG), stepy, miny);
            // append prediction to history state
            float tn = ct[b * PLTS + i];
            float wn = bl * tn;
            w2s[L] = wn;
            hxy[L] = make_float2(px, py);
            pu[L]  = make_float4(fmaf(c2, px * px + py * py, wn), -2.0f * c2 * px, -2.0f * c2 * py, 0.0f);
            // predicted_out[i][b] = (px,py)
            out[BB + (i * BB + b) * 2 + 0] = px;
            out[BB + (i * BB + b) * 2 + 1] = py;
        }
        __syncthreads();
    }

    // ---- GMM log-likelihood over the full 400-point history ----
    for (int j = tid; j < LMAX; j += BLOCK) Ejs[j] = fast_exp2(w2s[j]);
    __syncthreads();

    float acc = 0.0f;
    if (tid >= 1 && tid < LMAX) {
        const int i = tid;
        float xi = hxy[i].x, yi = hxy[i].y;
        float s = 0.0f, sE = 0.0f;
        for (int j = 0; j < i; ++j) {
            float2 h = hxy[j];
            float dx = xi - h.x, dy = yi - h.y;
            float sq = fmaf(dy, dy, dx * dx);
            s  += fast_exp2(fmaf(sq, c2, w2s[j]));
            sE += Ejs[j];
        }
        // logp_i = S + log(sum_j e^{beta t_j + c sq}) - log(sum_j e^{beta t_j})
        acc = Sc + LN2 * (fast_log2(s) - fast_log2(sE));
    }
    for (int o = 32; o > 0; o >>= 1) acc += __shfl_down(acc, o, 64);
    if (lane == 0) rv[wave] = acc;
    __syncthreads();
    if (tid == 0) {
        float tot = 0.0f;
        for (int w = 0; w < NWAVES; ++w) tot += rv[w];
        float2 h0 = hxy[0];
        tot += -0.5f * (h0.x * h0.x + h0.y * h0.y) - LOG2PI;  // logp0
        out[b] = tot;
    }
}

extern "C" void kernel_launch(void* const* d_in, const int* in_sizes, int n_in,
                              void* d_out, int out_size, void* d_ws, size_t ws_size,
                              hipStream_t stream) {
    const float* ct   = (const float*)d_in[0]; // curr_time
    const float* it   = (const float*)d_in[1]; // input_time
    const float* hd   = (const float*)d_in[2]; // history_data
    // d_in[3] expected_data, d_in[4] aux_state_in, d_in[5] aux_state_out: unused by the math
    const float* beta = (const float*)d_in[6];
    const float* lsig = (const float*)d_in[7];
    float* out = (float*)d_out;

    hipLaunchKernelGGL(spatio_kernel, dim3(BB), dim3(BLOCK), 0, stream,
                       ct, it, hd, beta, lsig, out);
}

// Round 2
// 325.191 us; speedup vs baseline: 1.1207x; 1.1207x over previous
//
#include <hip/hip_runtime.h>
#include <hip/hip_bf16.h>
#include <math.h>

// Problem constants: B=64, H=384, PLTS=16, D=2, grid 25x25.
#define BB    64
#define HH    384
#define PLTS  16
#define LMAX  (HH + PLTS)      // 400
#define NG    25
#define NC    (NG * NG)        // 625
#define BLOCK 640              // 10 waves
#define NWAVES (BLOCK / 64)
#define QB    4                // blocks per batch (j-chunks)

// d_ws layout in floats
#define PART_OFF 0                        // [2 parity][BB][QB][BLOCK]
#define PART_SZ  (2 * BB * QB * BLOCK)    // 327680 floats
#define GMM_OFF  (PART_OFF + PART_SZ)     // [BB][QB][LMAX][2]
#define GMM_SZ   (BB * QB * LMAX * 2)     // 204800 floats
#define BAR_OFF  (GMM_OFF + GMM_SZ)       // BB ints
#define WS_FLOATS (BAR_OFF + BB)

#if defined(__has_builtin) && __has_builtin(__builtin_amdgcn_exp2f)
static __device__ __forceinline__ float fast_exp2(float x) { return __builtin_amdgcn_exp2f(x); }
#else
static __device__ __forceinline__ float fast_exp2(float x) { return exp2f(x); }
#endif
#if defined(__has_builtin) && __has_builtin(__builtin_amdgcn_logf)
static __device__ __forceinline__ float fast_log2(float x) { return __builtin_amdgcn_logf(x); }
#else
static __device__ __forceinline__ float fast_log2(float x) { return log2f(x); }
#endif

// 4-block spin barrier per batch; monotonic counter, target = QB*phase.
// Safe: 256 blocks <= 256 CUs (10 waves, ~13KB LDS, low VGPR) => all resident.
static __device__ __forceinline__ void group_barrier(int* ctr, int target) {
    __syncthreads();
    if (threadIdx.x == 0) {
        __threadfence();   // release: publish my global writes (agent scope)
        __hip_atomic_fetch_add(ctr, 1, __ATOMIC_RELAXED, __HIP_MEMORY_SCOPE_AGENT);
        while (__hip_atomic_load(ctr, __ATOMIC_RELAXED, __HIP_MEMORY_SCOPE_AGENT) < target) {
            __builtin_amdgcn_s_sleep(8);
        }
        __threadfence();   // acquire: see others' writes
    }
    __syncthreads();
}

__global__ __launch_bounds__(BLOCK)
void spatio_kernel(const float* __restrict__ ct,    // curr_time   (B,16)
                   const float* __restrict__ it,    // input_time  (B,384)
                   const float* __restrict__ hd,    // history_data(B,384,2)
                   const float* __restrict__ beta_p,
                   const float* __restrict__ lsig_p,
                   float* __restrict__ out,         // [B loglik | (16,B,2) preds]
                   float* __restrict__ ws)
{
    // SoA for the candidate scan (uniform float4 broadcasts: 3 reads / 4 pts)
    __shared__ __align__(16) float u_s [LMAX];  // c2*(x^2+y^2) + bl*t   (-1e30 tail sentinel)
    __shared__ __align__(16) float px_s[LMAX];  // -2*c2*x
    __shared__ __align__(16) float py_s[LMAX];  // -2*c2*y
    __shared__ float  w2s[LMAX];   // bl * t_j
    __shared__ float2 hxy[LMAX];   // locations (gmm phase)
    __shared__ float  Ejs[LMAX];   // 2^{w2s[j]}  (gmm phase)
    __shared__ float  rv[NWAVES];
    __shared__ int    ri[NWAVES];
    __shared__ float  sb[4];

    const int bid  = blockIdx.x;
    const int q    = bid / BB;     // j-chunk id 0..3 (blocks of a batch are 64 apart)
    const int b    = bid % BB;     // batch
    const int tid  = threadIdx.x;
    const int lane = tid & 63;
    const int wave = tid >> 6;

    const float LOG2E  = 1.4426950408889634f;
    const float LN2    = 0.69314718055994531f;
    const float LOG2PI = 1.8378770664093453f;

    const float beta  = beta_p[0];
    const float lsig  = lsig_p[0];
    const float sigma = fast_exp2(lsig * LOG2E);
    const float cc    = -0.5f / (sigma * sigma);
    const float c2    = cc * LOG2E;              // base-2 coeff on sq
    const float bl    = beta * LOG2E;            // base-2 coeff on t
    const float Sc    = -2.0f * lsig - LOG2PI;   // d=2 Gaussian const

    float* part = ws + PART_OFF;
    int*   bar  = (int*)(ws + BAR_OFF);
    int    phase = 0;

    // ---- initial history into LDS (each block keeps the full per-batch state) ----
    for (int j = tid; j < HH; j += BLOCK) {
        float t = it[b * HH + j];
        float x = hd[(b * HH + j) * 2 + 0];
        float y = hd[(b * HH + j) * 2 + 1];
        float w = bl * t;
        w2s[j]  = w;
        hxy[j]  = make_float2(x, y);
        u_s[j]  = fmaf(c2, x * x + y * y, w);
        px_s[j] = -2.0f * c2 * x;
        py_s[j] = -2.0f * c2 * y;
    }
    for (int j = HH + tid; j < LMAX; j += BLOCK) {  // sentinel tail: exp -> 0
        u_s[j] = -1e30f; px_s[j] = 0.0f; py_s[j] = 0.0f;
    }

    // ---- grid bounds: min/max over history_data[:,0,:] and [:,1,:] across ALL batches ----
    if (tid < 64) {
        const float* p = hd + tid * (HH * 2);
        float p0x = p[0], p0y = p[1], p1x = p[2], p1y = p[3];
        float xmn = fminf(p0x, p0y), xmx = fmaxf(p0x, p0y);
        float ymn = fminf(p1x, p1y), ymx = fmaxf(p1x, p1y);
        for (int o = 32; o > 0; o >>= 1) {
            xmn = fminf(xmn, __shfl_down(xmn, o, 64));
            xmx = fmaxf(xmx, __shfl_down(xmx, o, 64));
            ymn = fminf(ymn, __shfl_down(ymn, o, 64));
            ymx = fmaxf(ymx, __shfl_down(ymx, o, 64));
        }
        if (tid == 0) { sb[0] = xmn; sb[1] = xmx; sb[2] = ymn; sb[3] = ymx; }
    }
    __syncthreads();

    const float minx = sb[0], maxx = sb[1], miny = sb[2], maxy = sb[3];
    const float stepx = (maxx - minx) * (1.0f / 24.0f);
    const float stepy = (maxy - miny) * (1.0f / 24.0f);

    float cx = 0.0f, cy = 0.0f, Ac = 0.0f;
    if (tid < NC) {
        int kx = tid % NG, ky = tid / NG;
        cx = fmaf((float)kx, stepx, minx);
        cy = fmaf((float)ky, stepy, miny);
        Ac = c2 * (cx * cx + cy * cy);
    }

    const float4* u4  = (const float4*)u_s;
    const float4* px4 = (const float4*)px_s;
    const float4* py4 = (const float4*)py_s;

    // ---- 16 sequential greedy steps; j-loop split across the 4 blocks ----
    for (int i = 0; i < PLTS; ++i) {
        const int L   = HH + i;
        const int nb4 = (L + 3) >> 2;
        const int gch = (nb4 + QB - 1) / QB;
        const int g0  = q * gch;
        const int g1  = min(nb4, g0 + gch);

        float* pslot = part + (((size_t)(i & 1) * BB + b) * QB + q) * BLOCK;
        if (tid < NC) {
            float s0 = 0.f, s1 = 0.f, s2 = 0.f, s3 = 0.f;
            for (int g = g0; g < g1; ++g) {
                float4 U = u4[g], PX = px4[g], PY = py4[g];
                s0 += fast_exp2(fmaf(PX.x, cx, fmaf(PY.x, cy, U.x + Ac)));
                s1 += fast_exp2(fmaf(PX.y, cx, fmaf(PY.y, cy, U.y + Ac)));
                s2 += fast_exp2(fmaf(PX.z, cx, fmaf(PY.z, cy, U.z + Ac)));
                s3 += fast_exp2(fmaf(PX.w, cx, fmaf(PY.w, cy, U.w + Ac)));
            }
            pslot[tid] = (s0 + s1) + (s2 + s3);
        }

        ++phase;
        group_barrier(&bar[b], QB * phase);

        // combine + argmin, redundantly in ALL blocks (deterministic fixed order)
        float v = __builtin_inff();
        int   idx = 0x7fffffff;
        if (tid < NC) {
            const float* pb = part + ((size_t)(i & 1) * BB + b) * QB * BLOCK;
            v = (pb[tid] + pb[BLOCK + tid]) + (pb[2 * BLOCK + tid] + pb[3 * BLOCK + tid]);
            idx = tid;
        }
        for (int o = 32; o > 0; o >>= 1) {
            float ov = __shfl_down(v, o, 64);
            int   oi = __shfl_down(idx, o, 64);
            if (ov < v || (ov == v && oi < idx)) { v = ov; idx = oi; }
        }
        if (lane == 0) { rv[wave] = v; ri[wave] = idx; }
        __syncthreads();
        if (tid == 0) {
            float bv = rv[0]; int bi = ri[0];
            for (int w = 1; w < NWAVES; ++w)
                if (rv[w] < bv || (rv[w] == bv && ri[w] < bi)) { bv = rv[w]; bi = ri[w]; }
            float px = fmaf((float)(bi % NG), stepx, minx);
            float py = fmaf((float)(bi / NG), stepy, miny);
            float tn = ct[b * PLTS + i];
            float wn = bl * tn;
            w2s[L]  = wn;
            hxy[L]  = make_float2(px, py);
            u_s[L]  = fmaf(c2, px * px + py * py, wn);
            px_s[L] = -2.0f * c2 * px;
            py_s[L] = -2.0f * c2 * py;
            if (q == 0) {
                out[BB + (i * BB + b) * 2 + 0] = px;
                out[BB + (i * BB + b) * 2 + 1] = py;
            }
        }
        __syncthreads();
    }

    // ---- GMM log-likelihood; per-i inner sum split across the 4 blocks ----
    for (int j = tid; j < LMAX; j += BLOCK) Ejs[j] = fast_exp2(w2s[j]);
    __syncthreads();

    if (tid >= 1 && tid < LMAX) {
        const int i  = tid;
        const int j0 = (q * i) / QB;
        const int j1 = ((q + 1) * i) / QB;
        float xi = hxy[i].x, yi = hxy[i].y;
        float sA = 0.0f, sE = 0.0f;
        for (int j = j0; j < j1; ++j) {
            float2 h = hxy[j];
            float dx = xi - h.x, dy = yi - h.y;
            float sq = fmaf(dy, dy, dx * dx);
            sA += fast_exp2(fmaf(sq, c2, w2s[j]));
            sE += Ejs[j];
        }
        size_t go = GMM_OFF + ((size_t)(b * QB + q) * LMAX + i) * 2;
        ws[go + 0] = sA;
        ws[go + 1] = sE;
    }

    ++phase;
    group_barrier(&bar[b], QB * phase);

    if (q == 0) {
        float acc = 0.0f;
        if (tid >= 1 && tid < LMAX) {
            size_t g0o = GMM_OFF + ((size_t)(b * QB + 0) * LMAX + tid) * 2;
            const float* w0 = ws + g0o;
            const float* w1 = w0 + (size_t)LMAX * 2;
            const float* w2 = w1 + (size_t)LMAX * 2;
            const float* w3 = w2 + (size_t)LMAX * 2;
            float sA = (w0[0] + w1[0]) + (w2[0] + w3[0]);
            float sE = (w0[1] + w1[1]) + (w2[1] + w3[1]);
            acc = Sc + LN2 * (fast_log2(sA) - fast_log2(sE));
        }
        for (int o = 32; o > 0; o >>= 1) acc += __shfl_down(acc, o, 64);
        if (lane == 0) rv[wave] = acc;
        __syncthreads();
        if (tid == 0) {
            float tot = 0.0f;
            for (int w = 0; w < NWAVES; ++w) tot += rv[w];
            float2 h0 = hxy[0];
            tot += -0.5f * (h0.x * h0.x + h0.y * h0.y) - LOG2PI;
            out[b] = tot;
        }
    }
}

extern "C" void kernel_launch(void* const* d_in, const int* in_sizes, int n_in,
                              void* d_out, int out_size, void* d_ws, size_t ws_size,
                              hipStream_t stream) {
    const float* ct   = (const float*)d_in[0];
    const float* it   = (const float*)d_in[1];
    const float* hd   = (const float*)d_in[2];
    const float* beta = (const float*)d_in[6];
    const float* lsig = (const float*)d_in[7];
    float* out = (float*)d_out;
    float* ws  = (float*)d_ws;

    // zero the barrier counters (graph-capturable, stream-ordered)
    hipMemsetAsync((char*)d_ws + BAR_OFF * sizeof(float), 0, BB * sizeof(int), stream);

    hipLaunchKernelGGL(spatio_kernel, dim3(BB * QB), dim3(BLOCK), 0, stream,
                       ct, it, hd, beta, lsig, out, ws);
}

// Round 3
// 119.190 us; speedup vs baseline: 3.0576x; 2.7283x over previous
//
#include <hip/hip_runtime.h>
#include <hip/hip_bf16.h>
#include <math.h>

// Problem constants: B=64, H=384, PLTS=16, D=2, grid 25x25.
#define BB    64
#define HH    384
#define PLTS  16
#define LMAX  (HH + PLTS)      // 400
#define NG    25
#define NC    (NG * NG)        // 625
#define BLOCK 640              // 10 waves; one block per batch
#define NWAVES (BLOCK / 64)

#if defined(__has_builtin) && __has_builtin(__builtin_amdgcn_exp2f)
static __device__ __forceinline__ float fast_exp2(float x) { return __builtin_amdgcn_exp2f(x); }
#else
static __device__ __forceinline__ float fast_exp2(float x) { return exp2f(x); }
#endif
#if defined(__has_builtin) && __has_builtin(__builtin_amdgcn_logf)
static __device__ __forceinline__ float fast_log2(float x) { return __builtin_amdgcn_logf(x); }
#else
static __device__ __forceinline__ float fast_log2(float x) { return log2f(x); }
#endif

__global__ __launch_bounds__(BLOCK)
void spatio_kernel(const float* __restrict__ ct,    // curr_time   (B,16)
                   const float* __restrict__ it,    // input_time  (B,384)
                   const float* __restrict__ hd,    // history_data(B,384,2)
                   const float* __restrict__ beta_p,
                   const float* __restrict__ lsig_p,
                   float* __restrict__ out)         // [B loglik | (16,B,2) preds]
{
    // SoA coefficient arrays for the ONE-TIME initial candidate scan.
    __shared__ __align__(16) float u_s [HH];  // c2*(x^2+y^2) + bl*t
    __shared__ __align__(16) float px_s[HH];  // -2*c2*x
    __shared__ __align__(16) float py_s[HH];  // -2*c2*y
    __shared__ float  w2s[LMAX];   // bl * t_j            (gmm phase)
    __shared__ float2 hxy[LMAX];   // history locations   (gmm phase)
    __shared__ float  Ejs[LMAX];   // 2^{w2s[j]}          (gmm phase)
    __shared__ float  rv[NWAVES];
    __shared__ int    ri[NWAVES];
    __shared__ float  sb[4];       // minx,maxx,miny,maxy
    __shared__ float  bc[3];       // broadcast: px, py, wn of chosen point

    const int b    = blockIdx.x;
    const int tid  = threadIdx.x;
    const int lane = tid & 63;
    const int wave = tid >> 6;

    const float LOG2E  = 1.4426950408889634f;
    const float LN2    = 0.69314718055994531f;
    const float LOG2PI = 1.8378770664093453f;

    const float beta  = beta_p[0];
    const float lsig  = lsig_p[0];
    const float sigma = fast_exp2(lsig * LOG2E);
    const float cc    = -0.5f / (sigma * sigma);
    const float c2    = cc * LOG2E;              // base-2 coeff on sq
    const float bl    = beta * LOG2E;            // base-2 coeff on t
    const float Sc    = -2.0f * lsig - LOG2PI;   // d=2 Gaussian const

    // ---- initial history into LDS ----
    for (int j = tid; j < HH; j += BLOCK) {
        float t = it[b * HH + j];
        float x = hd[(b * HH + j) * 2 + 0];
        float y = hd[(b * HH + j) * 2 + 1];
        float w = bl * t;
        w2s[j]  = w;
        hxy[j]  = make_float2(x, y);
        u_s[j]  = fmaf(c2, x * x + y * y, w);
        px_s[j] = -2.0f * c2 * x;
        py_s[j] = -2.0f * c2 * y;
    }

    // ---- grid bounds: min/max of history_data[:,0,:] / [:,1,:] across ALL batches ----
    if (tid < 64) {
        const float* p = hd + tid * (HH * 2);
        float p0x = p[0], p0y = p[1], p1x = p[2], p1y = p[3];
        float xmn = fminf(p0x, p0y), xmx = fmaxf(p0x, p0y);
        float ymn = fminf(p1x, p1y), ymx = fmaxf(p1x, p1y);
        for (int o = 32; o > 0; o >>= 1) {
            xmn = fminf(xmn, __shfl_down(xmn, o, 64));
            xmx = fmaxf(xmx, __shfl_down(xmx, o, 64));
            ymn = fminf(ymn, __shfl_down(ymn, o, 64));
            ymx = fmaxf(ymx, __shfl_down(ymx, o, 64));
        }
        if (tid == 0) { sb[0] = xmn; sb[1] = xmx; sb[2] = ymn; sb[3] = ymx; }
    }
    __syncthreads();

    const float minx = sb[0], maxx = sb[1], miny = sb[2], maxy = sb[3];
    const float stepx = (maxx - minx) * (1.0f / 24.0f);
    const float stepy = (maxy - miny) * (1.0f / 24.0f);

    float cx = 0.0f, cy = 0.0f, Ac = 0.0f;
    if (tid < NC) {
        int kx = tid % NG, ky = tid / NG;
        cx = fmaf((float)kx, stepx, minx);
        cy = fmaf((float)ky, stepy, miny);
        Ac = c2 * (cx * cx + cy * cy);
    }

    // ---- ONE-TIME initial score: S = sum_{j<384} 2^{w_j + c2*|c-h_j|^2} ----
    // (the per-step score is a RUNNING SUM: each step appends exactly one term)
    float S = 0.0f;
    if (tid < NC) {
        const float4* u4  = (const float4*)u_s;
        const float4* px4 = (const float4*)px_s;
        const float4* py4 = (const float4*)py_s;
        float s0 = 0.f, s1 = 0.f, s2 = 0.f, s3 = 0.f;
        #pragma unroll 8
        for (int g = 0; g < HH / 4; ++g) {      // compile-time trip count: deep ILP
            float4 U = u4[g], PX = px4[g], PY = py4[g];
            s0 += fast_exp2(fmaf(PX.x, cx, fmaf(PY.x, cy, U.x + Ac)));
            s1 += fast_exp2(fmaf(PX.y, cx, fmaf(PY.y, cy, U.y + Ac)));
            s2 += fast_exp2(fmaf(PX.z, cx, fmaf(PY.z, cy, U.z + Ac)));
            s3 += fast_exp2(fmaf(PX.w, cx, fmaf(PY.w, cy, U.w + Ac)));
        }
        S = (s0 + s1) + (s2 + s3);
    }

    // ---- 16 sequential steps: argmin(S) -> append point -> rank-1 update S ----
    for (int i = 0; i < PLTS; ++i) {
        float v   = (tid < NC) ? S   : __builtin_inff();
        int   idx = (tid < NC) ? tid : 0x7fffffff;
        for (int o = 32; o > 0; o >>= 1) {       // first-min tie-break = lowest idx
            float ov = __shfl_down(v, o, 64);
            int   oi = __shfl_down(idx, o, 64);
            if (ov < v || (ov == v && oi < idx)) { v = ov; idx = oi; }
        }
        if (lane == 0) { rv[wave] = v; ri[wave] = idx; }
        __syncthreads();
        if (tid == 0) {
            float bv = rv[0]; int bi = ri[0];
            for (int w = 1; w < NWAVES; ++w)
                if (rv[w] < bv || (rv[w] == bv && ri[w] < bi)) { bv = rv[w]; bi = ri[w]; }
            float px = fmaf((float)(bi % NG), stepx, minx);
            float py = fmaf((float)(bi / NG), stepy, miny);
            float tn = ct[b * PLTS + i];
            float wn = bl * tn;
            w2s[HH + i] = wn;
            hxy[HH + i] = make_float2(px, py);
            bc[0] = px; bc[1] = py; bc[2] = wn;
            out[BB + (i * BB + b) * 2 + 0] = px;
            out[BB + (i * BB + b) * 2 + 1] = py;
        }
        __syncthreads();
        if (tid < NC) {
            float dx = bc[0] - cx, dy = bc[1] - cy;
            S += fast_exp2(fmaf(c2, fmaf(dx, dx, dy * dy), bc[2]));
        }
    }

    // ---- GMM log-likelihood over the full 400-point history ----
    for (int j = tid; j < LMAX; j += BLOCK) Ejs[j] = fast_exp2(w2s[j]);
    __syncthreads();

    float acc = 0.0f;
    if (tid >= 1 && tid < LMAX) {
        const int i = tid;
        float xi = hxy[i].x, yi = hxy[i].y;
        float s = 0.0f, sE = 0.0f;
        #pragma unroll 4
        for (int j = 0; j < i; ++j) {
            float2 h = hxy[j];
            float dx = xi - h.x, dy = yi - h.y;
            float sq = fmaf(dy, dy, dx * dx);
            s  += fast_exp2(fmaf(sq, c2, w2s[j]));
            sE += Ejs[j];
        }
        acc = Sc + LN2 * (fast_log2(s) - fast_log2(sE));
    }
    for (int o = 32; o > 0; o >>= 1) acc += __shfl_down(acc, o, 64);
    if (lane == 0) rv[wave] = acc;
    __syncthreads();
    if (tid == 0) {
        float tot = 0.0f;
        for (int w = 0; w < NWAVES; ++w) tot += rv[w];
        float2 h0 = hxy[0];
        tot += -0.5f * (h0.x * h0.x + h0.y * h0.y) - LOG2PI;
        out[b] = tot;
    }
}

extern "C" void kernel_launch(void* const* d_in, const int* in_sizes, int n_in,
                              void* d_out, int out_size, void* d_ws, size_t ws_size,
                              hipStream_t stream) {
    const float* ct   = (const float*)d_in[0]; // curr_time
    const float* it   = (const float*)d_in[1]; // input_time
    const float* hd   = (const float*)d_in[2]; // history_data
    // d_in[3..5] (expected_data, aux_state_in, aux_state_out) are dead in the math
    const float* beta = (const float*)d_in[6];
    const float* lsig = (const float*)d_in[7];
    float* out = (float*)d_out;

    hipLaunchKernelGGL(spatio_kernel, dim3(BB), dim3(BLOCK), 0, stream,
                       ct, it, hd, beta, lsig, out);
}

// Round 5
// 104.041 us; speedup vs baseline: 3.5028x; 1.1456x over previous
//
#include <hip/hip_runtime.h>
#include <hip/hip_bf16.h>
#include <math.h>

// Problem constants: B=64, H=384, PLTS=16, D=2, grid 25x25.
#define BB    64
#define HH    384
#define PLTS  16
#define LMAX  (HH + PLTS)      // 400
#define NG    25
#define NC    (NG * NG)        // 625
#define BLOCK 640              // 10 waves; one block per batch
#define NWAVES (BLOCK / 64)
#define SPLIT 160              // rows >= SPLIT are split main/helper in GMM phase

#if defined(__has_builtin) && __has_builtin(__builtin_amdgcn_exp2f)
static __device__ __forceinline__ float fast_exp2(float x) { return __builtin_amdgcn_exp2f(x); }
#else
static __device__ __forceinline__ float fast_exp2(float x) { return exp2f(x); }
#endif
#if defined(__has_builtin) && __has_builtin(__builtin_amdgcn_logf)
static __device__ __forceinline__ float fast_log2(float x) { return __builtin_amdgcn_logf(x); }
#else
static __device__ __forceinline__ float fast_log2(float x) { return log2f(x); }
#endif

__global__ __launch_bounds__(BLOCK)
void spatio_kernel(const float* __restrict__ ct,    // curr_time   (B,16)
                   const float* __restrict__ it,    // input_time  (B,384)
                   const float* __restrict__ hd,    // history_data(B,384,2)
                   const float* __restrict__ beta_p,
                   const float* __restrict__ lsig_p,
                   float* __restrict__ out)         // [B loglik | (16,B,2) preds]
{
    // SoA coefficient arrays (extended to LMAX: step phase appends, GMM reuses)
    __shared__ __align__(16) float u_s [LMAX];  // c2*(x^2+y^2) + bl*t
    __shared__ __align__(16) float px_s[LMAX];  // -2*c2*x
    __shared__ __align__(16) float py_s[LMAX];  // -2*c2*y
    __shared__ float  w2s[LMAX];   // bl * t_j
    __shared__ float2 hxy[LMAX];   // history locations
    __shared__ float  S_s[NC];     // initial per-candidate scores
    __shared__ float  sA_h[LMAX];  // helper partial sums (rows >= SPLIT)
    __shared__ float  pre[LMAX];   // inclusive prefix of E_j = e^{beta t_j}
    __shared__ float  wsum[NWAVES];
    __shared__ float  rv[NWAVES];
    __shared__ float  sb[4];       // minx,maxx,miny,maxy

    const int b    = blockIdx.x;
    const int tid  = threadIdx.x;
    const int lane = tid & 63;
    const int wave = tid >> 6;

    const float LOG2E  = 1.4426950408889634f;
    const float LN2    = 0.69314718055994531f;
    const float LOG2PI = 1.8378770664093453f;
    const float INF    = __builtin_inff();

    const float beta  = beta_p[0];
    const float lsig  = lsig_p[0];
    const float sigma = fast_exp2(lsig * LOG2E);
    const float cc    = -0.5f / (sigma * sigma);
    const float c2    = cc * LOG2E;              // base-2 coeff on sq
    const float bl    = beta * LOG2E;            // base-2 coeff on t
    const float Sc    = -2.0f * lsig - LOG2PI;   // d=2 Gaussian const

    // ---- initial history into LDS ----
    for (int j = tid; j < HH; j += BLOCK) {
        float t = it[b * HH + j];
        float x = hd[(b * HH + j) * 2 + 0];
        float y = hd[(b * HH + j) * 2 + 1];
        float w = bl * t;
        w2s[j]  = w;
        hxy[j]  = make_float2(x, y);
        u_s[j]  = fmaf(c2, x * x + y * y, w);
        px_s[j] = -2.0f * c2 * x;
        py_s[j] = -2.0f * c2 * y;
    }

    // ---- grid bounds: min/max of history_data[:,0,:] / [:,1,:] across ALL batches ----
    if (tid < 64) {
        const float* p = hd + tid * (HH * 2);
        float p0x = p[0], p0y = p[1], p1x = p[2], p1y = p[3];
        float xmn = fminf(p0x, p0y), xmx = fmaxf(p0x, p0y);
        float ymn = fminf(p1x, p1y), ymx = fmaxf(p1x, p1y);
        for (int o = 32; o > 0; o >>= 1) {
            xmn = fminf(xmn, __shfl_down(xmn, o, 64));
            xmx = fmaxf(xmx, __shfl_down(xmx, o, 64));
            ymn = fminf(ymn, __shfl_down(ymn, o, 64));
            ymx = fmaxf(ymx, __shfl_down(ymx, o, 64));
        }
        if (tid == 0) { sb[0] = xmn; sb[1] = xmx; sb[2] = ymn; sb[3] = ymx; }
    }
    __syncthreads();

    const float minx = sb[0], maxx = sb[1], miny = sb[2], maxy = sb[3];
    const float stepx = (maxx - minx) * (1.0f / 24.0f);
    const float stepy = (maxy - miny) * (1.0f / 24.0f);

    // ---- ONE-TIME initial score S_c = sum_{j<384} 2^{w_j + c2*|c-h_j|^2} ----
    if (tid < NC) {
        int kx = tid % NG, ky = tid / NG;
        float cx = fmaf((float)kx, stepx, minx);
        float cy = fmaf((float)ky, stepy, miny);
        float Ac = c2 * (cx * cx + cy * cy);
        const float4* u4  = (const float4*)u_s;
        const float4* px4 = (const float4*)px_s;
        const float4* py4 = (const float4*)py_s;
        float s0 = 0.f, s1 = 0.f, s2 = 0.f, s3 = 0.f;
        #pragma unroll 8
        for (int g = 0; g < HH / 4; ++g) {
            float4 U = u4[g], PX = px4[g], PY = py4[g];
            s0 += fast_exp2(fmaf(PX.x, cx, fmaf(PY.x, cy, U.x + Ac)));
            s1 += fast_exp2(fmaf(PX.y, cx, fmaf(PY.y, cy, U.y + Ac)));
            s2 += fast_exp2(fmaf(PX.z, cx, fmaf(PY.z, cy, U.z + Ac)));
            s3 += fast_exp2(fmaf(PX.w, cx, fmaf(PY.w, cy, U.w + Ac)));
        }
        S_s[tid] = (s0 + s1) + (s2 + s3);
    }

    // preload step weights wn_i = bl*ct[b,i] into wave-0 lanes 0..15
    float wn_all = 0.0f;
    if (tid < PLTS) wn_all = bl * ct[b * PLTS + tid];
    __syncthreads();

    // ---- 16 sequential steps: SINGLE WAVE, registers only, no barriers ----
    if (wave == 0) {
        float Sv[10], cxk[10], cyk[10];
        const int cbase = lane * 10;
        #pragma unroll
        for (int k = 0; k < 10; ++k) {
            int c = cbase + k;
            if (c < NC) {
                Sv[k] = S_s[c];
                int ky = (int)((c + 0.5f) * 0.04f);
                int kx = c - 25 * ky;
                cxk[k] = fmaf((float)kx, stepx, minx);
                cyk[k] = fmaf((float)ky, stepy, miny);
            } else {
                Sv[k] = INF; cxk[k] = 0.0f; cyk[k] = 0.0f;
            }
        }
        for (int i = 0; i < PLTS; ++i) {
            // local argmin over my 10 candidates (first-min: strict <)
            float v = Sv[0]; int ik = 0;
            #pragma unroll
            for (int k = 1; k < 10; ++k)
                if (Sv[k] < v) { v = Sv[k]; ik = k; }
            int idx = cbase + ik;
            // butterfly argmin: all 64 lanes end with global (v, idx), lowest-idx tie-break
            #pragma unroll
            for (int o = 1; o < 64; o <<= 1) {
                float ov = __shfl_xor(v, o, 64);
                int   oi = __shfl_xor(idx, o, 64);
                if (ov < v || (ov == v && oi < idx)) { v = ov; idx = oi; }
            }
            int   ky = (int)((idx + 0.5f) * 0.04f);
            int   kx = idx - 25 * ky;
            float px = fmaf((float)kx, stepx, minx);
            float py = fmaf((float)ky, stepy, miny);
            float wn = __shfl(wn_all, i, 64);
            if (lane == 0) {
                const int L = HH + i;
                w2s[L]  = wn;
                hxy[L]  = make_float2(px, py);
                u_s[L]  = fmaf(c2, px * px + py * py, wn);
                px_s[L] = -2.0f * c2 * px;
                py_s[L] = -2.0f * c2 * py;
                out[BB + (i * BB + b) * 2 + 0] = px;
                out[BB + (i * BB + b) * 2 + 1] = py;
            }
            // rank-1 running-sum update of my 10 scores
            #pragma unroll
            for (int k = 0; k < 10; ++k) {
                float dx = px - cxk[k], dy = py - cyk[k];
                Sv[k] += fast_exp2(fmaf(c2, fmaf(dx, dx, dy * dy), wn));
            }
        }
    }
    __syncthreads();

    // ---- GMM log-likelihood; rows >= SPLIT divided main/helper for balance ----
    int row = 0, j0 = 0, j1 = 0;
    if (tid >= 1 && tid < LMAX) {            // main: row = tid
        row = tid; j0 = 0; j1 = (row >= SPLIT) ? (row >> 1) : row;
    } else if (tid >= LMAX) {                // helper: rows 160..399
        row = tid - 240; j0 = row >> 1; j1 = row;
    }
    float part = 0.0f;
    if (row > 0) {
        float2 hi = hxy[row];
        float xi = hi.x, yi = hi.y;
        float Ai = c2 * fmaf(xi, xi, yi * yi);
        float a0 = 0.f, a1 = 0.f;
        int j = j0;
        for (; j + 1 < j1; j += 2) {
            a0 += fast_exp2(fmaf(px_s[j],     xi, fmaf(py_s[j],     yi, u_s[j]     + Ai)));
            a1 += fast_exp2(fmaf(px_s[j + 1], xi, fmaf(py_s[j + 1], yi, u_s[j + 1] + Ai)));
        }
        if (j < j1)
            a0 += fast_exp2(fmaf(px_s[j], xi, fmaf(py_s[j], yi, u_s[j] + Ai)));
        part = a0 + a1;
    }
    if (tid >= LMAX) sA_h[row] = part;

    // block-wide inclusive prefix scan of E_j = 2^{w2s[j]}  (sE_i = pre[i-1])
    float x = (tid < LMAX) ? fast_exp2(w2s[tid]) : 0.0f;
    for (int o = 1; o < 64; o <<= 1) {
        float y = __shfl_up(x, o, 64);
        if (lane >= o) x += y;
    }
    if (lane == 63) wsum[wave] = x;
    __syncthreads();                          // also publishes sA_h
    float off = 0.0f;
    for (int w = 0; w < wave; ++w) off += wsum[w];
    if (tid < LMAX) pre[tid] = x + off;
    __syncthreads();

    float acc = 0.0f;
    if (tid >= 1 && tid < LMAX) {
        float tot = part + ((tid >= SPLIT) ? sA_h[tid] : 0.0f);
        acc = Sc + LN2 * (fast_log2(tot) - fast_log2(pre[tid - 1]));
    }
    for (int o = 32; o > 0; o >>= 1) acc += __shfl_down(acc, o, 64);
    if (lane == 0) rv[wave] = acc;
    __syncthreads();
    if (tid == 0) {
        float tot = 0.0f;
        for (int w = 0; w < NWAVES; ++w) tot += rv[w];
        float2 h0 = hxy[0];
        tot += -0.5f * (h0.x * h0.x + h0.y * h0.y) - LOG2PI;
        out[b] = tot;
    }
}

extern "C" void kernel_launch(void* const* d_in, const int* in_sizes, int n_in,
                              void* d_out, int out_size, void* d_ws, size_t ws_size,
                              hipStream_t stream) {
    const float* ct   = (const float*)d_in[0]; // curr_time
    const float* it   = (const float*)d_in[1]; // input_time
    const float* hd   = (const float*)d_in[2]; // history_data
    // d_in[3..5] (expected_data, aux_state_in, aux_state_out) are dead in the math
    const float* beta = (const float*)d_in[6];
    const float* lsig = (const float*)d_in[7];
    float* out = (float*)d_out;

    hipLaunchKernelGGL(spatio_kernel, dim3(BB), dim3(BLOCK), 0, stream,
                       ct, it, hd, beta, lsig, out);
}

// Round 6
// 94.228 us; speedup vs baseline: 3.8675x; 1.1041x over previous
//
#include <hip/hip_runtime.h>
#include <hip/hip_bf16.h>
#include <math.h>

// Problem constants: B=64, H=384, PLTS=16, D=2, grid 25x25.
#define BB    64
#define HH    384
#define PLTS  16
#define LMAX  (HH + PLTS)      // 400
#define NG    25
#define NC    (NG * NG)        // 625
#define BLOCK 1024             // 16 waves; one block per batch
#define NWAVES (BLOCK / 64)
#define NUNIT (3 * NC)         // 1875 scan units (3 parts x 128 points)

#if defined(__has_builtin) && __has_builtin(__builtin_amdgcn_exp2f)
static __device__ __forceinline__ float fast_exp2(float x) { return __builtin_amdgcn_exp2f(x); }
#else
static __device__ __forceinline__ float fast_exp2(float x) { return exp2f(x); }
#endif
#if defined(__has_builtin) && __has_builtin(__builtin_amdgcn_logf)
static __device__ __forceinline__ float fast_log2(float x) { return __builtin_amdgcn_logf(x); }
#else
static __device__ __forceinline__ float fast_log2(float x) { return log2f(x); }
#endif

__global__ __launch_bounds__(BLOCK)
void spatio_kernel(const float* __restrict__ ct,    // curr_time   (B,16)
                   const float* __restrict__ it,    // input_time  (B,384)
                   const float* __restrict__ hd,    // history_data(B,384,2)
                   const float* __restrict__ beta_p,
                   const float* __restrict__ lsig_p,
                   float* __restrict__ out)         // [B loglik | (16,B,2) preds]
{
    __shared__ __align__(16) float u_s [LMAX];  // c2*(x^2+y^2) + bl*t
    __shared__ __align__(16) float px_s[LMAX];  // -2*c2*x
    __shared__ __align__(16) float py_s[LMAX];  // -2*c2*y
    __shared__ float  w2s[LMAX];    // bl * t_j
    __shared__ float2 hxy[LMAX];    // history locations
    __shared__ float  Pscan[NUNIT]; // scan partials: unit u = cand + 625*part
    __shared__ float  Pg[BLOCK];    // GMM row-chunk partials (rows 1..383)
    __shared__ float  rowt[16];     // GMM row totals, rows 384..399
    __shared__ float  pre[LMAX];    // inclusive prefix of E_j = e^{beta t_j}
    __shared__ float  wsum[NWAVES];
    __shared__ float  rv[NWAVES];
    __shared__ float  sb[4];        // minx,maxx,miny,maxy

    const int b    = blockIdx.x;
    const int tid  = threadIdx.x;
    const int lane = tid & 63;
    const int wave = tid >> 6;

    const float LOG2E  = 1.4426950408889634f;
    const float LN2    = 0.69314718055994531f;
    const float LOG2PI = 1.8378770664093453f;
    const float INF    = __builtin_inff();

    const float beta  = beta_p[0];
    const float lsig  = lsig_p[0];
    const float sigma = fast_exp2(lsig * LOG2E);
    const float cc    = -0.5f / (sigma * sigma);
    const float c2    = cc * LOG2E;              // base-2 coeff on sq
    const float bl    = beta * LOG2E;            // base-2 coeff on t
    const float Sc    = -2.0f * lsig - LOG2PI;   // d=2 Gaussian const

    // ---- initial history into LDS ----
    for (int j = tid; j < HH; j += BLOCK) {
        float t = it[b * HH + j];
        float x = hd[(b * HH + j) * 2 + 0];
        float y = hd[(b * HH + j) * 2 + 1];
        float w = bl * t;
        w2s[j]  = w;
        hxy[j]  = make_float2(x, y);
        u_s[j]  = fmaf(c2, x * x + y * y, w);
        px_s[j] = -2.0f * c2 * x;
        py_s[j] = -2.0f * c2 * y;
    }

    // wave 0: preload all 16 step weights into registers (L2-broadcast loads)
    float wn_r[16];
    if (wave == 0) {
        const float4* ct4 = (const float4*)(ct + b * PLTS);
        float4 c0 = ct4[0], c1 = ct4[1], c2v = ct4[2], c3 = ct4[3];
        wn_r[0]=bl*c0.x;  wn_r[1]=bl*c0.y;  wn_r[2]=bl*c0.z;  wn_r[3]=bl*c0.w;
        wn_r[4]=bl*c1.x;  wn_r[5]=bl*c1.y;  wn_r[6]=bl*c1.z;  wn_r[7]=bl*c1.w;
        wn_r[8]=bl*c2v.x; wn_r[9]=bl*c2v.y; wn_r[10]=bl*c2v.z;wn_r[11]=bl*c2v.w;
        wn_r[12]=bl*c3.x; wn_r[13]=bl*c3.y; wn_r[14]=bl*c3.z; wn_r[15]=bl*c3.w;
    } else {
        #pragma unroll
        for (int k = 0; k < 16; ++k) wn_r[k] = 0.0f;
    }

    // ---- grid bounds: min/max of history_data[:,0,:] / [:,1,:] across ALL batches ----
    if (tid < 64) {
        const float* p = hd + tid * (HH * 2);
        float p0x = p[0], p0y = p[1], p1x = p[2], p1y = p[3];
        float xmn = fminf(p0x, p0y), xmx = fmaxf(p0x, p0y);
        float ymn = fminf(p1x, p1y), ymx = fmaxf(p1x, p1y);
        for (int o = 32; o > 0; o >>= 1) {
            xmn = fminf(xmn, __shfl_down(xmn, o, 64));
            xmx = fmaxf(xmx, __shfl_down(xmx, o, 64));
            ymn = fminf(ymn, __shfl_down(ymn, o, 64));
            ymx = fmaxf(ymx, __shfl_down(ymx, o, 64));
        }
        if (tid == 0) { sb[0] = xmn; sb[1] = xmx; sb[2] = ymn; sb[3] = ymx; }
    }
    __syncthreads();

    const float minx = sb[0], maxx = sb[1], miny = sb[2], maxy = sb[3];
    const float stepx = (maxx - minx) * (1.0f / 24.0f);
    const float stepy = (maxy - miny) * (1.0f / 24.0f);

    // ---- initial scores, 3-way split: unit u = cand + 625*part, 32 float4-groups ----
    {
        const float4* u4  = (const float4*)u_s;
        const float4* px4 = (const float4*)px_s;
        const float4* py4 = (const float4*)py_s;
        #pragma unroll
        for (int rep = 0; rep < 2; ++rep) {
            int u = tid + rep * BLOCK;
            if (u < NUNIT) {
                int cand = u % NC;
                int part = u / NC;
                int kx = cand % NG, ky = cand / NG;
                float cx = fmaf((float)kx, stepx, minx);
                float cy = fmaf((float)ky, stepy, miny);
                float Ac = c2 * (cx * cx + cy * cy);
                int g0 = part * 32;
                float s0 = 0.f, s1 = 0.f, s2 = 0.f, s3 = 0.f;
                #pragma unroll 8
                for (int g = g0; g < g0 + 32; ++g) {
                    float4 U = u4[g], PX = px4[g], PY = py4[g];
                    s0 += fast_exp2(fmaf(PX.x, cx, fmaf(PY.x, cy, U.x + Ac)));
                    s1 += fast_exp2(fmaf(PX.y, cx, fmaf(PY.y, cy, U.y + Ac)));
                    s2 += fast_exp2(fmaf(PX.z, cx, fmaf(PY.z, cy, U.z + Ac)));
                    s3 += fast_exp2(fmaf(PX.w, cx, fmaf(PY.w, cy, U.w + Ac)));
                }
                Pscan[u] = (s0 + s1) + (s2 + s3);
            }
        }
    }
    __syncthreads();

    // ==== FORK: wave 0 runs the 16 sequential steps; waves 1..15 run GMM rows 1..383 ====
    if (wave == 0) {
        float Sv[10], cxk[10], cyk[10];
        const int cbase = lane * 10;
        #pragma unroll
        for (int k = 0; k < 10; ++k) {
            int c = cbase + k;
            if (c < NC) {
                Sv[k] = Pscan[c] + Pscan[c + NC] + Pscan[c + 2 * NC];
                int ky = (int)((c + 0.5f) * 0.04f);
                int kx = c - 25 * ky;
                cxk[k] = fmaf((float)kx, stepx, minx);
                cyk[k] = fmaf((float)ky, stepy, miny);
            } else {
                Sv[k] = INF; cxk[k] = 0.0f; cyk[k] = 0.0f;
            }
        }
        #pragma unroll
        for (int i = 0; i < PLTS; ++i) {
            float v = Sv[0]; int ik = 0;
            #pragma unroll
            for (int k = 1; k < 10; ++k)
                if (Sv[k] < v) { v = Sv[k]; ik = k; }
            int idx = cbase + ik;
            #pragma unroll
            for (int o = 1; o < 64; o <<= 1) {
                float ov = __shfl_xor(v, o, 64);
                int   oi = __shfl_xor(idx, o, 64);
                if (ov < v || (ov == v && oi < idx)) { v = ov; idx = oi; }
            }
            int   ky = (int)((idx + 0.5f) * 0.04f);
            int   kx = idx - 25 * ky;
            float px = fmaf((float)kx, stepx, minx);
            float py = fmaf((float)ky, stepy, miny);
            float wn = wn_r[i];
            if (lane == 0) {
                const int L = HH + i;
                w2s[L]  = wn;
                hxy[L]  = make_float2(px, py);
                u_s[L]  = fmaf(c2, px * px + py * py, wn);
                px_s[L] = -2.0f * c2 * px;
                py_s[L] = -2.0f * c2 * py;
                out[BB + (i * BB + b) * 2 + 0] = px;
                out[BB + (i * BB + b) * 2 + 1] = py;
            }
            #pragma unroll
            for (int k = 0; k < 10; ++k) {
                float dx = px - cxk[k], dy = py - cyk[k];
                Sv[k] += fast_exp2(fmaf(c2, fmaf(dx, dx, dy * dy), wn));
            }
        }
    } else {
        // GMM rows 1..383, chunks of <=100 pairs. t2 in [0,960):
        //   t2   0..99  : row = t2+1         c=0        (rows 1..100, 1 chunk)
        //   t2 100..299 : row = 101+(u>>1)   c=u&1      (rows 101..200, 2 chunks)
        //   t2 300..599 : row = 201+u/3      c=u-3*(u/3)(rows 201..300, 3 chunks)
        //   t2 600..931 : row = 301+(u>>2)   c=u&3      (rows 301..383, 4 chunks)
        const int t2 = tid - 64;
        int row = 0, c = 0;
        if (t2 < 100)      { row = t2 + 1; c = 0; }
        else if (t2 < 300) { int u = t2 - 100; row = 101 + (u >> 1); c = u & 1; }
        else if (t2 < 600) { int u = t2 - 300; int q = u / 3; row = 201 + q; c = u - 3 * q; }
        else if (t2 < 932) { int u = t2 - 600; row = 301 + (u >> 2); c = u & 3; }
        float part = 0.0f;
        if (row > 0) {
            int j0 = c * 100;
            int j1 = min(row, j0 + 100);
            float2 hi = hxy[row];
            float xi = hi.x, yi = hi.y;
            float Ai = c2 * fmaf(xi, xi, yi * yi);
            float a0 = 0.f, a1 = 0.f;
            int j = j0;
            for (; j + 1 < j1; j += 2) {
                a0 += fast_exp2(fmaf(px_s[j],     xi, fmaf(py_s[j],     yi, u_s[j]     + Ai)));
                a1 += fast_exp2(fmaf(px_s[j + 1], xi, fmaf(py_s[j + 1], yi, u_s[j + 1] + Ai)));
            }
            if (j < j1)
                a0 += fast_exp2(fmaf(px_s[j], xi, fmaf(py_s[j], yi, u_s[j] + Ai)));
            part = a0 + a1;
        }
        Pg[tid] = part;
    }
    __syncthreads();

    // ---- GMM tail rows 384..399: row = 384+wave, 64 chunks of <=7 pairs ----
    {
        const int row = HH + wave;           // 384..399
        int j0 = lane * 7;
        int j1 = min(row, j0 + 7);
        float2 hi = hxy[row];
        float xi = hi.x, yi = hi.y;
        float Ai = c2 * fmaf(xi, xi, yi * yi);
        float part = 0.0f;
        for (int j = j0; j < j1; ++j)
            part += fast_exp2(fmaf(px_s[j], xi, fmaf(py_s[j], yi, u_s[j] + Ai)));
        for (int o = 32; o > 0; o >>= 1) part += __shfl_down(part, o, 64);
        if (lane == 0) rowt[wave] = part;
    }

    // ---- block-wide inclusive prefix scan of E_j = 2^{w2s[j]} ----
    float x = (tid < LMAX) ? fast_exp2(w2s[tid]) : 0.0f;
    for (int o = 1; o < 64; o <<= 1) {
        float y = __shfl_up(x, o, 64);
        if (lane >= o) x += y;
    }
    if (lane == 63) wsum[wave] = x;
    __syncthreads();                          // publishes rowt + wsum
    float off = 0.0f;
    for (int w = 0; w < wave; ++w) off += wsum[w];
    if (tid < LMAX) pre[tid] = x + off;
    __syncthreads();

    // ---- per-row logp + block reduction ----
    float acc = 0.0f;
    if (tid >= 1 && tid < LMAX) {
        const int row = tid;
        float tot;
        if (row <= 100)      { tot = Pg[64 + row - 1]; }
        else if (row <= 200) { int base = 64 + 100 + (row - 101) * 2;
                               tot = Pg[base] + Pg[base + 1]; }
        else if (row <= 300) { int base = 64 + 300 + (row - 201) * 3;
                               tot = Pg[base] + Pg[base + 1] + Pg[base + 2]; }
        else if (row <= 383) { int base = 64 + 600 + (row - 301) * 4;
                               tot = (Pg[base] + Pg[base + 1]) + (Pg[base + 2] + Pg[base + 3]); }
        else                 { tot = rowt[row - HH]; }
        acc = Sc + LN2 * (fast_log2(tot) - fast_log2(pre[row - 1]));
    }
    for (int o = 32; o > 0; o >>= 1) acc += __shfl_down(acc, o, 64);
    if (lane == 0) rv[wave] = acc;
    __syncthreads();
    if (tid == 0) {
        float tot = 0.0f;
        for (int w = 0; w < NWAVES; ++w) tot += rv[w];
        float2 h0 = hxy[0];
        tot += -0.5f * (h0.x * h0.x + h0.y * h0.y) - LOG2PI;
        out[b] = tot;
    }
}

extern "C" void kernel_launch(void* const* d_in, const int* in_sizes, int n_in,
                              void* d_out, int out_size, void* d_ws, size_t ws_size,
                              hipStream_t stream) {
    const float* ct   = (const float*)d_in[0]; // curr_time
    const float* it   = (const float*)d_in[1]; // input_time
    const float* hd   = (const float*)d_in[2]; // history_data
    // d_in[3..5] (expected_data, aux_state_in, aux_state_out) are dead in the math
    const float* beta = (const float*)d_in[6];
    const float* lsig = (const float*)d_in[7];
    float* out = (float*)d_out;

    hipLaunchKernelGGL(spatio_kernel, dim3(BB), dim3(BLOCK), 0, stream,
                       ct, it, hd, beta, lsig, out);
}

// Round 7
// 89.312 us; speedup vs baseline: 4.0804x; 1.0550x over previous
//
#include <hip/hip_runtime.h>
#include <hip/hip_bf16.h>
#include <math.h>

// Problem constants: B=64, H=384, PLTS=16, D=2, grid 25x25.
#define BB    64
#define HH    384
#define PLTS  16
#define LMAX  (HH + PLTS)      // 400
#define NG    25
#define NC    (NG * NG)        // 625
#define BLOCK 1024             // 16 waves; one block per batch
#define NWAVES (BLOCK / 64)
#define FSTR  388              // padded row stride (floats) for FxT/FyT
#define KHALF 192              // K split in two halves for the 1250 GEMM units
#define NUNIT (2 * NC)         // 1250

#if defined(__has_builtin) && __has_builtin(__builtin_amdgcn_exp2f)
static __device__ __forceinline__ float fast_exp2(float x) { return __builtin_amdgcn_exp2f(x); }
#else
static __device__ __forceinline__ float fast_exp2(float x) { return exp2f(x); }
#endif
#if defined(__has_builtin) && __has_builtin(__builtin_amdgcn_logf)
static __device__ __forceinline__ float fast_log2(float x) { return __builtin_amdgcn_logf(x); }
#else
static __device__ __forceinline__ float fast_log2(float x) { return log2f(x); }
#endif

__global__ __launch_bounds__(BLOCK)
void spatio_kernel(const float* __restrict__ ct,    // curr_time   (B,16)
                   const float* __restrict__ it,    // input_time  (B,384)
                   const float* __restrict__ hd,    // history_data(B,384,2)
                   const float* __restrict__ beta_p,
                   const float* __restrict__ lsig_p,
                   float* __restrict__ out)         // [B loglik | (16,B,2) preds]
{
    // Separable scan factors: S[kx][ky] = sum_j FxT[kx][j] * FyT[ky][j]
    __shared__ __align__(16) float FxT[NG][FSTR];  // 2^{w_j + c2(cx-hx_j)^2}
    __shared__ __align__(16) float FyT[NG][FSTR];  // 2^{c2(cy-hy_j)^2}
    __shared__ __align__(16) float u_s [LMAX];  // c2*(x^2+y^2) + bl*t  (GMM)
    __shared__ __align__(16) float px_s[LMAX];  // -2*c2*x
    __shared__ __align__(16) float py_s[LMAX];  // -2*c2*y
    __shared__ float  w2s[LMAX];    // bl * t_j
    __shared__ float2 hxy[LMAX];    // history locations
    __shared__ float  P[NUNIT];     // GEMM partials: unit u = c + 625*h
    __shared__ float  Pg[BLOCK];    // GMM row-chunk partials (rows 1..383)
    __shared__ float  rowt[16];     // GMM row totals, rows 384..399
    __shared__ float  pre[LMAX];    // inclusive prefix of E_j = e^{beta t_j}
    __shared__ float  wsum[NWAVES];
    __shared__ float  rv[NWAVES];
    __shared__ float  sb[4];        // minx,maxx,miny,maxy

    const int b    = blockIdx.x;
    const int tid  = threadIdx.x;
    const int lane = tid & 63;
    const int wave = tid >> 6;

    const float LOG2E  = 1.4426950408889634f;
    const float LN2    = 0.69314718055994531f;
    const float LOG2PI = 1.8378770664093453f;
    const float INF    = __builtin_inff();

    const float beta  = beta_p[0];
    const float lsig  = lsig_p[0];
    const float sigma = fast_exp2(lsig * LOG2E);
    const float cc    = -0.5f / (sigma * sigma);
    const float c2    = cc * LOG2E;              // base-2 coeff on sq
    const float bl    = beta * LOG2E;            // base-2 coeff on t
    const float Sc    = -2.0f * lsig - LOG2PI;   // d=2 Gaussian const

    // ---- initial history into LDS ----
    for (int j = tid; j < HH; j += BLOCK) {
        float t = it[b * HH + j];
        float x = hd[(b * HH + j) * 2 + 0];
        float y = hd[(b * HH + j) * 2 + 1];
        float w = bl * t;
        w2s[j]  = w;
        hxy[j]  = make_float2(x, y);
        u_s[j]  = fmaf(c2, x * x + y * y, w);
        px_s[j] = -2.0f * c2 * x;
        py_s[j] = -2.0f * c2 * y;
    }

    // wave 0: preload all 16 step weights into registers
    float wn_r[16];
    if (wave == 0) {
        const float4* ct4 = (const float4*)(ct + b * PLTS);
        float4 c0 = ct4[0], c1 = ct4[1], c2v = ct4[2], c3 = ct4[3];
        wn_r[0]=bl*c0.x;  wn_r[1]=bl*c0.y;  wn_r[2]=bl*c0.z;  wn_r[3]=bl*c0.w;
        wn_r[4]=bl*c1.x;  wn_r[5]=bl*c1.y;  wn_r[6]=bl*c1.z;  wn_r[7]=bl*c1.w;
        wn_r[8]=bl*c2v.x; wn_r[9]=bl*c2v.y; wn_r[10]=bl*c2v.z;wn_r[11]=bl*c2v.w;
        wn_r[12]=bl*c3.x; wn_r[13]=bl*c3.y; wn_r[14]=bl*c3.z; wn_r[15]=bl*c3.w;
    } else {
        #pragma unroll
        for (int k = 0; k < 16; ++k) wn_r[k] = 0.0f;
    }

    // ---- grid bounds: min/max of history_data[:,0,:] / [:,1,:] across ALL batches ----
    if (tid < 64) {
        const float* p = hd + tid * (HH * 2);
        float p0x = p[0], p0y = p[1], p1x = p[2], p1y = p[3];
        float xmn = fminf(p0x, p0y), xmx = fmaxf(p0x, p0y);
        float ymn = fminf(p1x, p1y), ymx = fmaxf(p1x, p1y);
        for (int o = 32; o > 0; o >>= 1) {
            xmn = fminf(xmn, __shfl_down(xmn, o, 64));
            xmx = fmaxf(xmx, __shfl_down(xmx, o, 64));
            ymn = fminf(ymn, __shfl_down(ymn, o, 64));
            ymx = fmaxf(ymx, __shfl_down(ymx, o, 64));
        }
        if (tid == 0) { sb[0] = xmn; sb[1] = xmx; sb[2] = ymn; sb[3] = ymx; }
    }
    __syncthreads();

    const float minx = sb[0], maxx = sb[1], miny = sb[2], maxy = sb[3];
    const float stepx = (maxx - minx) * (1.0f / 24.0f);
    const float stepy = (maxy - miny) * (1.0f / 24.0f);

    // ---- separable factor precompute: 2 x 25 x 384 exps ----
    for (int idx = tid; idx < NG * HH; idx += BLOCK) {
        int row = idx / HH;           // grid index 0..24
        int j   = idx - row * HH;     // history point 0..383
        float2 h = hxy[j];
        float cxr = fmaf((float)row, stepx, minx);
        float cyr = fmaf((float)row, stepy, miny);
        float dx = cxr - h.x;
        float dy = cyr - h.y;
        FxT[row][j] = fast_exp2(fmaf(c2 * dx, dx, w2s[j]));
        FyT[row][j] = fast_exp2(c2 * dy * dy);
    }
    __syncthreads();

    // ---- GEMM: S[c] = sum_j FxT[kx][j]*FyT[ky][j]; 1250 units of K=192 ----
    #pragma unroll
    for (int rep = 0; rep < 2; ++rep) {
        int u = tid + rep * BLOCK;
        if (u < NUNIT) {
            int h    = (u >= NC) ? 1 : 0;
            int c    = u - h * NC;
            int ky   = c / NG;
            int kx   = c - NG * ky;
            const float4* fx4 = (const float4*)&FxT[kx][0];
            const float4* fy4 = (const float4*)&FyT[ky][0];
            int g0 = h * (KHALF / 4);
            float s0 = 0.f, s1 = 0.f, s2 = 0.f, s3 = 0.f;
            #pragma unroll 8
            for (int g = g0; g < g0 + KHALF / 4; ++g) {
                float4 a = fx4[g], bv = fy4[g];
                s0 = fmaf(a.x, bv.x, s0);
                s1 = fmaf(a.y, bv.y, s1);
                s2 = fmaf(a.z, bv.z, s2);
                s3 = fmaf(a.w, bv.w, s3);
            }
            P[u] = (s0 + s1) + (s2 + s3);
        }
    }
    __syncthreads();

    // ==== FORK: wave 0 runs the 16 sequential steps; waves 1..15 run GMM rows 1..383 ====
    if (wave == 0) {
        float Sv[10], cxk[10], cyk[10];
        const int cbase = lane * 10;
        #pragma unroll
        for (int k = 0; k < 10; ++k) {
            int c = cbase + k;
            if (c < NC) {
                Sv[k] = P[c] + P[c + NC];
                int ky = (int)((c + 0.5f) * 0.04f);
                int kx = c - 25 * ky;
                cxk[k] = fmaf((float)kx, stepx, minx);
                cyk[k] = fmaf((float)ky, stepy, miny);
            } else {
                Sv[k] = INF; cxk[k] = 0.0f; cyk[k] = 0.0f;
            }
        }
        #pragma unroll
        for (int i = 0; i < PLTS; ++i) {
            float v = Sv[0]; int ik = 0;
            #pragma unroll
            for (int k = 1; k < 10; ++k)
                if (Sv[k] < v) { v = Sv[k]; ik = k; }
            int idx = cbase + ik;
            #pragma unroll
            for (int o = 1; o < 64; o <<= 1) {
                float ov = __shfl_xor(v, o, 64);
                int   oi = __shfl_xor(idx, o, 64);
                if (ov < v || (ov == v && oi < idx)) { v = ov; idx = oi; }
            }
            int   ky = (int)((idx + 0.5f) * 0.04f);
            int   kx = idx - 25 * ky;
            float px = fmaf((float)kx, stepx, minx);
            float py = fmaf((float)ky, stepy, miny);
            float wn = wn_r[i];
            if (lane == 0) {
                const int L = HH + i;
                w2s[L]  = wn;
                hxy[L]  = make_float2(px, py);
                u_s[L]  = fmaf(c2, px * px + py * py, wn);
                px_s[L] = -2.0f * c2 * px;
                py_s[L] = -2.0f * c2 * py;
                out[BB + (i * BB + b) * 2 + 0] = px;
                out[BB + (i * BB + b) * 2 + 1] = py;
            }
            #pragma unroll
            for (int k = 0; k < 10; ++k) {
                float dx = px - cxk[k], dy = py - cyk[k];
                Sv[k] += fast_exp2(fmaf(c2, fmaf(dx, dx, dy * dy), wn));
            }
        }
    } else {
        // GMM rows 1..383, chunks of <=100 pairs. t2 in [0,960):
        const int t2 = tid - 64;
        int row = 0, c = 0;
        if (t2 < 100)      { row = t2 + 1; c = 0; }
        else if (t2 < 300) { int u = t2 - 100; row = 101 + (u >> 1); c = u & 1; }
        else if (t2 < 600) { int u = t2 - 300; int q = u / 3; row = 201 + q; c = u - 3 * q; }
        else if (t2 < 932) { int u = t2 - 600; row = 301 + (u >> 2); c = u & 3; }
        float part = 0.0f;
        if (row > 0) {
            int j0 = c * 100;
            int j1 = min(row, j0 + 100);
            float2 hi = hxy[row];
            float xi = hi.x, yi = hi.y;
            float Ai = c2 * fmaf(xi, xi, yi * yi);
            float a0 = 0.f, a1 = 0.f;
            int j = j0;
            for (; j + 1 < j1; j += 2) {
                a0 += fast_exp2(fmaf(px_s[j],     xi, fmaf(py_s[j],     yi, u_s[j]     + Ai)));
                a1 += fast_exp2(fmaf(px_s[j + 1], xi, fmaf(py_s[j + 1], yi, u_s[j + 1] + Ai)));
            }
            if (j < j1)
                a0 += fast_exp2(fmaf(px_s[j], xi, fmaf(py_s[j], yi, u_s[j] + Ai)));
            part = a0 + a1;
        }
        Pg[tid] = part;
    }
    __syncthreads();

    // ---- GMM tail rows 384..399: row = 384+wave, 64 chunks of <=7 pairs ----
    {
        const int row = HH + wave;           // 384..399
        int j0 = lane * 7;
        int j1 = min(row, j0 + 7);
        float2 hi = hxy[row];
        float xi = hi.x, yi = hi.y;
        float Ai = c2 * fmaf(xi, xi, yi * yi);
        float part = 0.0f;
        for (int j = j0; j < j1; ++j)
            part += fast_exp2(fmaf(px_s[j], xi, fmaf(py_s[j], yi, u_s[j] + Ai)));
        for (int o = 32; o > 0; o >>= 1) part += __shfl_down(part, o, 64);
        if (lane == 0) rowt[wave] = part;
    }

    // ---- block-wide inclusive prefix scan of E_j = 2^{w2s[j]} ----
    float x = (tid < LMAX) ? fast_exp2(w2s[tid]) : 0.0f;
    for (int o = 1; o < 64; o <<= 1) {
        float y = __shfl_up(x, o, 64);
        if (lane >= o) x += y;
    }
    if (lane == 63) wsum[wave] = x;
    __syncthreads();                          // publishes rowt + wsum
    float off = 0.0f;
    for (int w = 0; w < wave; ++w) off += wsum[w];
    if (tid < LMAX) pre[tid] = x + off;
    __syncthreads();

    // ---- per-row logp + block reduction ----
    float acc = 0.0f;
    if (tid >= 1 && tid < LMAX) {
        const int row = tid;
        float tot;
        if (row <= 100)      { tot = Pg[64 + row - 1]; }
        else if (row <= 200) { int base = 64 + 100 + (row - 101) * 2;
                               tot = Pg[base] + Pg[base + 1]; }
        else if (row <= 300) { int base = 64 + 300 + (row - 201) * 3;
                               tot = Pg[base] + Pg[base + 1] + Pg[base + 2]; }
        else if (row <= 383) { int base = 64 + 600 + (row - 301) * 4;
                               tot = (Pg[base] + Pg[base + 1]) + (Pg[base + 2] + Pg[base + 3]); }
        else                 { tot = rowt[row - HH]; }
        acc = Sc + LN2 * (fast_log2(tot) - fast_log2(pre[row - 1]));
    }
    for (int o = 32; o > 0; o >>= 1) acc += __shfl_down(acc, o, 64);
    if (lane == 0) rv[wave] = acc;
    __syncthreads();
    if (tid == 0) {
        float tot = 0.0f;
        for (int w = 0; w < NWAVES; ++w) tot += rv[w];
        float2 h0 = hxy[0];
        tot += -0.5f * (h0.x * h0.x + h0.y * h0.y) - LOG2PI;
        out[b] = tot;
    }
}

extern "C" void kernel_launch(void* const* d_in, const int* in_sizes, int n_in,
                              void* d_out, int out_size, void* d_ws, size_t ws_size,
                              hipStream_t stream) {
    const float* ct   = (const float*)d_in[0]; // curr_time
    const float* it   = (const float*)d_in[1]; // input_time
    const float* hd   = (const float*)d_in[2]; // history_data
    // d_in[3..5] (expected_data, aux_state_in, aux_state_out) are dead in the math
    const float* beta = (const float*)d_in[6];
    const float* lsig = (const float*)d_in[7];
    float* out = (float*)d_out;

    hipLaunchKernelGGL(spatio_kernel, dim3(BB), dim3(BLOCK), 0, stream,
                       ct, it, hd, beta, lsig, out);
}

// Round 9
// 81.624 us; speedup vs baseline: 4.4647x; 1.0942x over previous
//
#include <hip/hip_runtime.h>
#include <hip/hip_bf16.h>
#include <math.h>

// Problem constants: B=64, H=384, PLTS=16, D=2, grid 25x25.
#define BB    64
#define HH    384
#define PLTS  16
#define LMAX  (HH + PLTS)      // 400
#define NG    25
#define NC    (NG * NG)        // 625
#define BLOCK 1024             // 16 waves; one block per batch
#define NWAVES (BLOCK / 64)
#define FSTR  388              // padded row stride (floats) for FxT/FyT
#define NCHUNK 8               // K split (384 = 8 x 48)
#define KC    48
#define GEMM_UNITS (125 * NCHUNK)   // (5 kx-groups x 25 ky) x 8 chunks = 1000

#if defined(__has_builtin) && __has_builtin(__builtin_amdgcn_exp2f)
static __device__ __forceinline__ float fast_exp2(float x) { return __builtin_amdgcn_exp2f(x); }
#else
static __device__ __forceinline__ float fast_exp2(float x) { return exp2f(x); }
#endif
#if defined(__has_builtin) && __has_builtin(__builtin_amdgcn_logf)
static __device__ __forceinline__ float fast_log2(float x) { return __builtin_amdgcn_logf(x); }
#else
static __device__ __forceinline__ float fast_log2(float x) { return log2f(x); }
#endif

#if defined(__has_builtin)
#if __has_builtin(__builtin_amdgcn_update_dpp) && __has_builtin(__builtin_amdgcn_readlane)
#define HAS_DPP 1
#endif
#endif

// Wave-wide min, result broadcast to all 64 lanes. Bit-exact (fminf returns an operand).
static __device__ __forceinline__ float wave_min_all(float v) {
#ifdef HAS_DPP
    float r = v;
    // row_shr:1,2,4,8 then row_bcast15 (0x142), row_bcast31 (0x143); old=self -> masked lanes no-op
    #define DPP_STEP(ctrl) { int ri = __float_as_int(r); \
        int si = __builtin_amdgcn_update_dpp(ri, ri, (ctrl), 0xf, 0xf, false); \
        r = fminf(r, __int_as_float(si)); }
    DPP_STEP(0x111) DPP_STEP(0x112) DPP_STEP(0x114) DPP_STEP(0x118)
    DPP_STEP(0x142) DPP_STEP(0x143)
    #undef DPP_STEP
    return __int_as_float(__builtin_amdgcn_readlane(__float_as_int(r), 63));
#else
    for (int o = 1; o < 64; o <<= 1) v = fminf(v, __shfl_xor(v, o, 64));
    return v;
#endif
}

static __device__ __forceinline__ int lane_bcast_int(int x, int src_lane) {
#ifdef HAS_DPP
    return __builtin_amdgcn_readlane(x, src_lane);
#else
    return __shfl(x, src_lane, 64);
#endif
}

__global__ __launch_bounds__(BLOCK)
void spatio_kernel(const float* __restrict__ ct,    // curr_time   (B,16)
                   const float* __restrict__ it,    // input_time  (B,384)
                   const float* __restrict__ hd,    // history_data(B,384,2)
                   const float* __restrict__ beta_p,
                   const float* __restrict__ lsig_p,
                   float* __restrict__ out)         // [B loglik | (16,B,2) preds]
{
    // Separable scan factors: S[kx][ky] = sum_j FxT[kx][j] * FyT[ky][j]
    __shared__ __align__(16) float FxT[NG][FSTR];  // 2^{w_j + c2(cx-hx_j)^2}
    __shared__ __align__(16) float FyT[NG][FSTR];  // 2^{c2(cy-hy_j)^2}
    __shared__ __align__(16) float u_s [LMAX];  // c2*(x^2+y^2) + bl*t  (GMM)
    __shared__ __align__(16) float px_s[LMAX];  // -2*c2*x
    __shared__ __align__(16) float py_s[LMAX];  // -2*c2*y
    __shared__ float  w2s[LMAX];    // bl * t_j
    __shared__ float2 hxy[LMAX];    // history locations
    __shared__ __align__(16) float P[NC * NCHUNK]; // GEMM partials: P[c*8+chunk]
    __shared__ float  Pg[BLOCK];    // GMM row-chunk partials (rows 1..383)
    __shared__ float  rowt[16];     // GMM row totals, rows 384..399
    __shared__ float  pre[LMAX];    // inclusive prefix of E_j = e^{beta t_j}
    __shared__ float  wsum[NWAVES];
    __shared__ float  rv[NWAVES];
    __shared__ float  sb[4];        // minx,maxx,miny,maxy

    const int b    = blockIdx.x;
    const int tid  = threadIdx.x;
    const int lane = tid & 63;
    const int wave = tid >> 6;

    const float LOG2E  = 1.4426950408889634f;
    const float LN2    = 0.69314718055994531f;
    const float LOG2PI = 1.8378770664093453f;
    const float INF    = __builtin_inff();

    const float beta  = beta_p[0];
    const float lsig  = lsig_p[0];
    const float sigma = fast_exp2(lsig * LOG2E);
    const float cc    = -0.5f / (sigma * sigma);
    const float c2    = cc * LOG2E;              // base-2 coeff on sq
    const float bl    = beta * LOG2E;            // base-2 coeff on t
    const float Sc    = -2.0f * lsig - LOG2PI;   // d=2 Gaussian const

    // ---- initial history into LDS ----
    for (int j = tid; j < HH; j += BLOCK) {
        float t = it[b * HH + j];
        float x = hd[(b * HH + j) * 2 + 0];
        float y = hd[(b * HH + j) * 2 + 1];
        float w = bl * t;
        w2s[j]  = w;
        hxy[j]  = make_float2(x, y);
        u_s[j]  = fmaf(c2, x * x + y * y, w);
        px_s[j] = -2.0f * c2 * x;
        py_s[j] = -2.0f * c2 * y;
    }

    // wave 0: preload all 16 step weights into registers
    float wn_r[16];
    if (wave == 0) {
        const float4* ct4 = (const float4*)(ct + b * PLTS);
        float4 c0 = ct4[0], c1 = ct4[1], c2v = ct4[2], c3 = ct4[3];
        wn_r[0]=bl*c0.x;  wn_r[1]=bl*c0.y;  wn_r[2]=bl*c0.z;  wn_r[3]=bl*c0.w;
        wn_r[4]=bl*c1.x;  wn_r[5]=bl*c1.y;  wn_r[6]=bl*c1.z;  wn_r[7]=bl*c1.w;
        wn_r[8]=bl*c2v.x; wn_r[9]=bl*c2v.y; wn_r[10]=bl*c2v.z;wn_r[11]=bl*c2v.w;
        wn_r[12]=bl*c3.x; wn_r[13]=bl*c3.y; wn_r[14]=bl*c3.z; wn_r[15]=bl*c3.w;
    } else {
        #pragma unroll
        for (int k = 0; k < 16; ++k) wn_r[k] = 0.0f;
    }

    // ---- grid bounds: min/max of history_data[:,0,:] / [:,1,:] across ALL batches ----
    if (tid < 64) {
        const float* p = hd + tid * (HH * 2);
        float p0x = p[0], p0y = p[1], p1x = p[2], p1y = p[3];
        float xmn = fminf(p0x, p0y), xmx = fmaxf(p0x, p0y);
        float ymn = fminf(p1x, p1y), ymx = fmaxf(p1x, p1y);
        for (int o = 32; o > 0; o >>= 1) {
            xmn = fminf(xmn, __shfl_down(xmn, o, 64));
            xmx = fmaxf(xmx, __shfl_down(xmx, o, 64));
            ymn = fminf(ymn, __shfl_down(ymn, o, 64));
            ymx = fmaxf(ymx, __shfl_down(ymx, o, 64));
        }
        if (tid == 0) { sb[0] = xmn; sb[1] = xmx; sb[2] = ymn; sb[3] = ymx; }
    }
    __syncthreads();

    const float minx = sb[0], maxx = sb[1], miny = sb[2], maxy = sb[3];
    const float stepx = (maxx - minx) * (1.0f / 24.0f);
    const float stepy = (maxy - miny) * (1.0f / 24.0f);

    // ---- separable factor precompute: 2 x 25 x 384 exps ----
    for (int idx = tid; idx < NG * HH; idx += BLOCK) {
        int row = idx / HH;           // grid index 0..24
        int j   = idx - row * HH;     // history point 0..383
        float2 h = hxy[j];
        float cxr = fmaf((float)row, stepx, minx);
        float cyr = fmaf((float)row, stepy, miny);
        float dx = cxr - h.x;
        float dy = cyr - h.y;
        FxT[row][j] = fast_exp2(fmaf(c2 * dx, dx, w2s[j]));
        FyT[row][j] = fast_exp2(c2 * dy * dy);
    }
    __syncthreads();

    // ---- GEMM: 5x1 kx-tiles x K-chunks. unit u = kxg + 5*ky + 125*chunk ----
    if (tid < GEMM_UNITS) {
        int chunk = tid / 125;
        int r     = tid - chunk * 125;
        int ky    = r / 5;
        int kxg   = r - ky * 5;           // 5 consecutive lanes share ky -> Fx broadcast
        const int g0 = chunk * (KC / 4);  // 12 float4-groups per chunk
        const float4* fy4 = (const float4*)&FyT[ky][0];
        const float4* fx0 = (const float4*)&FxT[5 * kxg + 0][0];
        const float4* fx1 = (const float4*)&FxT[5 * kxg + 1][0];
        const float4* fx2 = (const float4*)&FxT[5 * kxg + 2][0];
        const float4* fx3 = (const float4*)&FxT[5 * kxg + 3][0];
        const float4* fx4 = (const float4*)&FxT[5 * kxg + 4][0];
        float4 A0 = {0,0,0,0}, A1 = {0,0,0,0}, A2 = {0,0,0,0}, A3 = {0,0,0,0}, A4 = {0,0,0,0};
        #pragma unroll
        for (int g = g0; g < g0 + KC / 4; ++g) {
            float4 bv = fy4[g];
            float4 x0 = fx0[g];
            A0.x = fmaf(x0.x, bv.x, A0.x); A0.y = fmaf(x0.y, bv.y, A0.y);
            A0.z = fmaf(x0.z, bv.z, A0.z); A0.w = fmaf(x0.w, bv.w, A0.w);
            float4 x1 = fx1[g];
            A1.x = fmaf(x1.x, bv.x, A1.x); A1.y = fmaf(x1.y, bv.y, A1.y);
            A1.z = fmaf(x1.z, bv.z, A1.z); A1.w = fmaf(x1.w, bv.w, A1.w);
            float4 x2 = fx2[g];
            A2.x = fmaf(x2.x, bv.x, A2.x); A2.y = fmaf(x2.y, bv.y, A2.y);
            A2.z = fmaf(x2.z, bv.z, A2.z); A2.w = fmaf(x2.w, bv.w, A2.w);
            float4 x3 = fx3[g];
            A3.x = fmaf(x3.x, bv.x, A3.x); A3.y = fmaf(x3.y, bv.y, A3.y);
            A3.z = fmaf(x3.z, bv.z, A3.z); A3.w = fmaf(x3.w, bv.w, A3.w);
            float4 x4 = fx4[g];
            A4.x = fmaf(x4.x, bv.x, A4.x); A4.y = fmaf(x4.y, bv.y, A4.y);
            A4.z = fmaf(x4.z, bv.z, A4.z); A4.w = fmaf(x4.w, bv.w, A4.w);
        }
        const int cb = 5 * kxg + 25 * ky;      // candidate index of tile element 0
        P[(cb + 0) * NCHUNK + chunk] = (A0.x + A0.y) + (A0.z + A0.w);
        P[(cb + 1) * NCHUNK + chunk] = (A1.x + A1.y) + (A1.z + A1.w);
        P[(cb + 2) * NCHUNK + chunk] = (A2.x + A2.y) + (A2.z + A2.w);
        P[(cb + 3) * NCHUNK + chunk] = (A3.x + A3.y) + (A3.z + A3.w);
        P[(cb + 4) * NCHUNK + chunk] = (A4.x + A4.y) + (A4.z + A4.w);
    }
    __syncthreads();

    // ==== FORK: wave 0 runs the 16 sequential steps; waves 1..15 run GMM rows 1..383 ====
    if (wave == 0) {
        float Sv[10], cxk[10], cyk[10];
        const int cbase = lane * 10;
        #pragma unroll
        for (int k = 0; k < 10; ++k) {
            int c = cbase + k;
            if (c < NC) {
                const float4* p4 = (const float4*)&P[c * NCHUNK];
                float4 a = p4[0], d = p4[1];
                Sv[k] = ((a.x + a.y) + (a.z + a.w)) + ((d.x + d.y) + (d.z + d.w));
                int ky = (int)((c + 0.5f) * 0.04f);
                int kx = c - 25 * ky;
                cxk[k] = fmaf((float)kx, stepx, minx);
                cyk[k] = fmaf((float)ky, stepy, miny);
            } else {
                Sv[k] = INF; cxk[k] = 0.0f; cyk[k] = 0.0f;
            }
        }
        #pragma unroll
        for (int i = 0; i < PLTS; ++i) {
            // local min (value only), then wave-uniform min via DPP, then first-occurrence pick
            float vl = Sv[0];
            #pragma unroll
            for (int k = 1; k < 10; ++k) vl = fminf(vl, Sv[k]);
            float vmin = wave_min_all(vl);
            unsigned long long m = __ballot(vl == vmin);
            int win = (int)__ffsll((unsigned long long)m) - 1;   // lowest lane holding the min
            int kl = 9;
            #pragma unroll
            for (int k = 9; k >= 0; --k) if (Sv[k] == vmin) kl = k;  // lowest k on each lane
            int kwin = lane_bcast_int(kl, win);
            int idx  = win * 10 + kwin;
            int   ky = (int)((idx + 0.5f) * 0.04f);
            int   kx = idx - 25 * ky;
            float px = fmaf((float)kx, stepx, minx);
            float py = fmaf((float)ky, stepy, miny);
            float wn = wn_r[i];
            if (lane == 0) {
                const int L = HH + i;
                w2s[L]  = wn;
                hxy[L]  = make_float2(px, py);
                u_s[L]  = fmaf(c2, px * px + py * py, wn);
                px_s[L] = -2.0f * c2 * px;
                py_s[L] = -2.0f * c2 * py;
                out[BB + (i * BB + b) * 2 + 0] = px;
                out[BB + (i * BB + b) * 2 + 1] = py;
            }
            #pragma unroll
            for (int k = 0; k < 10; ++k) {
                float dx = px - cxk[k], dy = py - cyk[k];
                Sv[k] += fast_exp2(fmaf(c2, fmaf(dx, dx, dy * dy), wn));
            }
        }
    } else {
        // GMM rows 1..383, chunks of <=100 pairs. t2 in [0,960):
        const int t2 = tid - 64;
        int row = 0, c = 0;
        if (t2 < 100)      { row = t2 + 1; c = 0; }
        else if (t2 < 300) { int u = t2 - 100; row = 101 + (u >> 1); c = u & 1; }
        else if (t2 < 600) { int u = t2 - 300; int q = u / 3; row = 201 + q; c = u - 3 * q; }
        else if (t2 < 932) { int u = t2 - 600; row = 301 + (u >> 2); c = u & 3; }
        float part = 0.0f;
        if (row > 0) {
            int j0 = c * 100;                 // multiple of 4
            int j1 = min(row, j0 + 100);
            float2 hi = hxy[row];
            float xi = hi.x, yi = hi.y;
            float Ai = c2 * fmaf(xi, xi, yi * yi);
            const float4* u4g  = (const float4*)u_s;
            const float4* px4g = (const float4*)px_s;
            const float4* py4g = (const float4*)py_s;
            float a0 = 0.f, a1 = 0.f, a2 = 0.f, a3 = 0.f;
            int j = j0;
            for (; j + 4 <= j1; j += 4) {
                int g = j >> 2;
                float4 U = u4g[g], PX = px4g[g], PY = py4g[g];
                a0 += fast_exp2(fmaf(PX.x, xi, fmaf(PY.x, yi, U.x + Ai)));
                a1 += fast_exp2(fmaf(PX.y, xi, fmaf(PY.y, yi, U.y + Ai)));
                a2 += fast_exp2(fmaf(PX.z, xi, fmaf(PY.z, yi, U.z + Ai)));
                a3 += fast_exp2(fmaf(PX.w, xi, fmaf(PY.w, yi, U.w + Ai)));
            }
            for (; j < j1; ++j)
                a0 += fast_exp2(fmaf(px_s[j], xi, fmaf(py_s[j], yi, u_s[j] + Ai)));
            part = (a0 + a1) + (a2 + a3);
        }
        Pg[tid] = part;
    }
    __syncthreads();

    // ---- GMM tail rows 384..399: row = 384+wave, 64 chunks of <=7 pairs ----
    {
        const int row = HH + wave;           // 384..399
        int j0 = lane * 7;
        int j1 = min(row, j0 + 7);
        float2 hi = hxy[row];
        float xi = hi.x, yi = hi.y;
        float Ai = c2 * fmaf(xi, xi, yi * yi);
        float part = 0.0f;
        for (int j = j0; j < j1; ++j)
            part += fast_exp2(fmaf(px_s[j], xi, fmaf(py_s[j], yi, u_s[j] + Ai)));
        for (int o = 32; o > 0; o >>= 1) part += __shfl_down(part, o, 64);
        if (lane == 0) rowt[wave] = part;
    }

    // ---- block-wide inclusive prefix scan of E_j = 2^{w2s[j]} ----
    float x = (tid < LMAX) ? fast_exp2(w2s[tid]) : 0.0f;
    for (int o = 1; o < 64; o <<= 1) {
        float y = __shfl_up(x, o, 64);
        if (lane >= o) x += y;
    }
    if (lane == 63) wsum[wave] = x;
    __syncthreads();                          // publishes rowt + wsum
    float off = 0.0f;
    for (int w = 0; w < wave; ++w) off += wsum[w];
    if (tid < LMAX) pre[tid] = x + off;
    __syncthreads();

    // ---- per-row logp + block reduction ----
    float acc = 0.0f;
    if (tid >= 1 && tid < LMAX) {
        const int row = tid;
        float tot;
        if (row <= 100)      { tot = Pg[64 + row - 1]; }
        else if (row <= 200) { int base = 64 + 100 + (row - 101) * 2;
                               tot = Pg[base] + Pg[base + 1]; }
        else if (row <= 300) { int base = 64 + 300 + (row - 201) * 3;
                               tot = Pg[base] + Pg[base + 1] + Pg[base + 2]; }
        else if (row <= 383) { int base = 64 + 600 + (row - 301) * 4;
                               tot = (Pg[base] + Pg[base + 1]) + (Pg[base + 2] + Pg[base + 3]); }
        else                 { tot = rowt[row - HH]; }
        acc = Sc + LN2 * (fast_log2(tot) - fast_log2(pre[row - 1]));
    }
    for (int o = 32; o > 0; o >>= 1) acc += __shfl_down(acc, o, 64);
    if (lane == 0) rv[wave] = acc;
    __syncthreads();
    if (tid == 0) {
        float tot = 0.0f;
        for (int w = 0; w < NWAVES; ++w) tot += rv[w];
        float2 h0 = hxy[0];
        tot += -0.5f * (h0.x * h0.x + h0.y * h0.y) - LOG2PI;
        out[b] = tot;
    }
}

extern "C" void kernel_launch(void* const* d_in, const int* in_sizes, int n_in,
                              void* d_out, int out_size, void* d_ws, size_t ws_size,
                              hipStream_t stream) {
    const float* ct   = (const float*)d_in[0]; // curr_time
    const float* it   = (const float*)d_in[1]; // input_time
    const float* hd   = (const float*)d_in[2]; // history_data
    // d_in[3..5] (expected_data, aux_state_in, aux_state_out) are dead in the math
    const float* beta = (const float*)d_in[6];
    const float* lsig = (const float*)d_in[7];
    float* out = (float*)d_out;

    hipLaunchKernelGGL(spatio_kernel, dim3(BB), dim3(BLOCK), 0, stream,
                       ct, it, hd, beta, lsig, out);
}